// Round 2
// baseline (123.295 us; speedup 1.0000x reference)
//
#include <hip/hip_runtime.h>
#include <hip/hip_bf16.h>

#define B_ 8192
#define D_ 256
#define EPS_ 1e-6f
#define MARGIN_ 1.0f
#define NT_ 64                               // 128-row tiles
#define NBLK_ (NT_ * (NT_ + 1) / 2)          // 2080
#define CEPS_ ((float)D_ * EPS_ * EPS_)

typedef float floatx4 __attribute__((ext_vector_type(4)));
typedef __bf16 bf16x4 __attribute__((ext_vector_type(4)));
typedef __bf16 bf16x8 __attribute__((ext_vector_type(8)));

typedef __attribute__((address_space(3))) unsigned int lds_uint_t;
typedef __attribute__((address_space(1))) const unsigned int g_uint_t;

__device__ __forceinline__ void g2l16(const unsigned short* g, unsigned short* l) {
    __builtin_amdgcn_global_load_lds((g_uint_t*)g, (lds_uint_t*)l, 16, 0, 0);
}

// ws float-region layout (after 4 MB bf16 matrix)
#define XBF_BYTES (B_ * D_ * 2)
#define OFF_P 0
#define OFF_Q 8192
#define OFF_T0 16384
#define OFF_T1 32768
#define OFF_PP 49152
#define OFF_QQ 49280
#define OFF_CNT 49408
#define OFF_PMIN 49536
#define OFF_QMIN 49600
#define OFF_ACC 49664

// ---------------- prep: one block per 128-row tile ----------------
__global__ __launch_bounds__(256) void prep_kernel(
    const float* __restrict__ x, const int* __restrict__ label,
    __bf16* __restrict__ xbf, float* __restrict__ fws) {
    float* p = fws + OFF_P;  float* q = fws + OFF_Q;
    float* T0 = fws + OFF_T0; float* T1 = fws + OFF_T1;
    float* Pp = fws + OFF_PP; float* Qq = fws + OFF_QQ;
    float* cntf = fws + OFF_CNT;
    float* pmin = fws + OFF_PMIN; float* qmin = fws + OFF_QMIN;
    float* acc = fws + OFF_ACC;

    __shared__ float sp[128], sqv[128];
    __shared__ int lab_s[128];
    __shared__ float red[2][7];

    const int ti = blockIdx.x;
    const int tid = threadIdx.x, wave = tid >> 6, lane = tid & 63;

    // pass 1: per-row sq-norm/row-sum + bf16 cast (wave handles 32 rows)
    for (int i = 0; i < 32; ++i) {
        const int rloc = wave * 32 + i;
        const int row = ti * 128 + rloc;
        const float4 v = *(const float4*)(x + (size_t)row * D_ + lane * 4);
        float sq = v.x * v.x + v.y * v.y + v.z * v.z + v.w * v.w;
        float rs = v.x + v.y + v.z + v.w;
        #pragma unroll
        for (int off = 32; off; off >>= 1) {
            sq += __shfl_down(sq, off);
            rs += __shfl_down(rs, off);
        }
        if (lane == 0) {
            const float pv = sq + 2.0f * EPS_ * rs;
            const float qv = sq - 2.0f * EPS_ * rs;
            p[row] = pv; q[row] = qv; sp[rloc] = pv; sqv[rloc] = qv;
        }
        bf16x4 h = { (__bf16)v.x, (__bf16)v.y, (__bf16)v.z, (__bf16)v.w };
        *(bf16x4*)(xbf + (size_t)row * D_ + lane * 4) = h;
    }
    if (tid < 128) lab_s[tid] = label[ti * 128 + tid];
    __syncthreads();

    // pass 2a: per-tile label-partitioned scalar sums (waves 0,1)
    if (wave < 2) {
        const int rloc = wave * 64 + lane;
        const float pv = sp[rloc], qv = sqv[rloc];
        const int l = lab_s[rloc];
        float p0 = l ? 0.f : pv, p1 = l ? pv : 0.f;
        float q0 = l ? 0.f : qv, q1 = l ? qv : 0.f;
        float c0 = l ? 0.f : 1.f;
        float pm = pv, qm = qv;
        #pragma unroll
        for (int off = 32; off; off >>= 1) {
            p0 += __shfl_down(p0, off); p1 += __shfl_down(p1, off);
            q0 += __shfl_down(q0, off); q1 += __shfl_down(q1, off);
            c0 += __shfl_down(c0, off);
            pm = fminf(pm, __shfl_down(pm, off));
            qm = fminf(qm, __shfl_down(qm, off));
        }
        if (lane == 0) {
            red[wave][0] = p0; red[wave][1] = p1; red[wave][2] = q0;
            red[wave][3] = q1; red[wave][4] = c0; red[wave][5] = pm; red[wave][6] = qm;
        }
    }
    // pass 2b: fp32 label-partitioned column sums (T vectors)
    {
        float t0 = 0.f, t1 = 0.f;
        const int col = tid;
        for (int rr = 0; rr < 128; ++rr) {
            const float v = x[(size_t)(ti * 128 + rr) * D_ + col];
            if (lab_s[rr]) t1 += v; else t0 += v;
        }
        T0[ti * 256 + col] = t0; T1[ti * 256 + col] = t1;
    }
    __syncthreads();
    if (tid == 0) {
        const float c0 = red[0][4] + red[1][4];
        Pp[ti * 2 + 0] = red[0][0] + red[1][0]; Pp[ti * 2 + 1] = red[0][1] + red[1][1];
        Qq[ti * 2 + 0] = red[0][2] + red[1][2]; Qq[ti * 2 + 1] = red[0][3] + red[1][3];
        cntf[ti * 2 + 0] = c0; cntf[ti * 2 + 1] = 128.0f - c0;
        pmin[ti] = fminf(red[0][5], red[1][5]);
        qmin[ti] = fminf(red[0][6], red[1][6]);
        if (ti == 0) acc[0] = 0.0f;
    }
}

// ---------------- tile: gram + detection (off-diag) / exact (diag) ----------------
__global__ __launch_bounds__(256, 4) void tile_kernel(
    const unsigned short* __restrict__ xbf, const int* __restrict__ label,
    const float* __restrict__ fws, float* __restrict__ acc) {
    const float* p = fws + OFF_P;  const float* q = fws + OFF_Q;
    const float* pmin = fws + OFF_PMIN; const float* qmin = fws + OFF_QMIN;

    int b = blockIdx.x;
    int ti = 0, rem = NT_;
    while (b >= rem) { b -= rem; ++ti; --rem; }
    const int tj = ti + b;
    const int i0 = ti * 128, j0 = tj * 128;

    __shared__ __align__(16) unsigned short As[128 * 64];
    __shared__ __align__(16) unsigned short Bs[128 * 64];

    const int tid = threadIdx.x, wave = tid >> 6, lane = tid & 63;
    const int quad = lane >> 4, r = lane & 15;
    const int wm = wave >> 1, wn = wave & 1;

    // staging source (XOR-chunk swizzle so ds_read_b128 is conflict-free)
    const int r8 = lane >> 3, cch = lane & 7;
    const int sw = ((cch ^ r8) * 8);
    const unsigned short* ga = xbf + (size_t)(i0 + wave * 32 + r8) * D_ + sw;
    const unsigned short* gb = xbf + (size_t)(j0 + wave * 32 + r8) * D_ + sw;

    // fragment LDS offsets (shorts); k2=32 toggles via ^32
    int a_off[4], b_off[4];
    const int swr = (quad ^ (r & 7)) * 8;
    #pragma unroll
    for (int mt = 0; mt < 4; ++mt) a_off[mt] = (wm * 64 + mt * 16 + r) * 64 + swr;
    #pragma unroll
    for (int nt = 0; nt < 4; ++nt) b_off[nt] = (wn * 64 + nt * 16 + r) * 64 + swr;

    floatx4 accv[16];
    #pragma unroll
    for (int t = 0; t < 16; ++t) accv[t] = (floatx4)0.0f;

    for (int k0 = 0; k0 < D_; k0 += 64) {
        __syncthreads();
        #pragma unroll
        for (int ps = 0; ps < 4; ++ps) {
            g2l16(ga + k0 + ps * 8 * D_, &As[(wave * 32 + ps * 8) * 64]);
            g2l16(gb + k0 + ps * 8 * D_, &Bs[(wave * 32 + ps * 8) * 64]);
        }
        __syncthreads();
        #pragma unroll
        for (int k2 = 0; k2 < 2; ++k2) {
            const int kx = k2 * 32;
            bf16x8 af[4], bfr[4];
            #pragma unroll
            for (int mt = 0; mt < 4; ++mt) af[mt] = *(const bf16x8*)&As[a_off[mt] ^ kx];
            #pragma unroll
            for (int nt = 0; nt < 4; ++nt) bfr[nt] = *(const bf16x8*)&Bs[b_off[nt] ^ kx];
            #pragma unroll
            for (int mt = 0; mt < 4; ++mt)
                #pragma unroll
                for (int nt = 0; nt < 4; ++nt)
                    accv[mt * 4 + nt] = __builtin_amdgcn_mfma_f32_16x16x32_bf16(
                        af[mt], bfr[nt], accv[mt * 4 + nt], 0, 0, 0);
        }
    }

    if (ti != tj) {
        // detection only: any pair with sq_eps < 1 (i.e. gram > thr)?
        float m = -1e30f;
        #pragma unroll
        for (int t = 0; t < 16; ++t)
            m = fmaxf(m, fmaxf(fmaxf(accv[t][0], accv[t][1]), fmaxf(accv[t][2], accv[t][3])));
        const float thr = (pmin[ti] + qmin[tj] + CEPS_ - 1.0f) * 0.5f;
        if (__any(m > thr)) {
            // exact slow path (expected never taken)
            float s = 0.0f;
            #pragma unroll
            for (int mt = 0; mt < 4; ++mt)
                #pragma unroll
                for (int nt = 0; nt < 4; ++nt)
                    #pragma unroll
                    for (int reg = 0; reg < 4; ++reg) {
                        const int gi = i0 + wm * 64 + mt * 16 + quad * 4 + reg;
                        const int gj = j0 + wn * 64 + nt * 16 + r;
                        const float sq = p[gi] + q[gj] + CEPS_ - 2.0f * accv[mt * 4 + nt][reg];
                        if (sq < 1.0f && label[gi] != label[gj]) {
                            const float d = sqrtf(fmaxf(sq, 1e-12f));
                            const float h = fmaxf(MARGIN_ - d, 0.0f);
                            s += h * h;
                        }
                    }
            #pragma unroll
            for (int off = 32; off; off >>= 1) s += __shfl_down(s, off);
            if (lane == 0) atomicAdd(acc, s);
        }
    } else {
        // diagonal: exact per-pair, strict upper triangle
        float s = 0.0f;
        #pragma unroll
        for (int mt = 0; mt < 4; ++mt)
            #pragma unroll
            for (int nt = 0; nt < 4; ++nt)
                #pragma unroll
                for (int reg = 0; reg < 4; ++reg) {
                    const int il = wm * 64 + mt * 16 + quad * 4 + reg;
                    const int jl = wn * 64 + nt * 16 + r;
                    if (il < jl) {
                        const int gi = i0 + il, gj = j0 + jl;
                        const float sq = p[gi] + q[gj] + CEPS_ - 2.0f * accv[mt * 4 + nt][reg];
                        const float d = sqrtf(fmaxf(sq, 1e-12f));
                        float v;
                        if (label[gi] == label[gj]) v = d * d;
                        else { const float h = fmaxf(MARGIN_ - d, 0.0f); v = h * h; }
                        s += v;
                    }
                }
        #pragma unroll
        for (int off = 32; off; off >>= 1) s += __shfl_down(s, off);
        if (lane == 0) atomicAdd(acc, s);
    }
}

// ---------------- finalize: analytic cross-tile same-label sum ----------------
__global__ __launch_bounds__(256) void finalize_kernel(
    const float* __restrict__ fws, float* __restrict__ out) {
    const float* T0 = fws + OFF_T0; const float* T1 = fws + OFF_T1;
    const float* Pp = fws + OFF_PP; const float* Qq = fws + OFF_QQ;
    const float* cntf = fws + OFF_CNT;
    const float* acc = fws + OFF_ACC;

    __shared__ float colred[256];
    const int tid = threadIdx.x;
    float s0 = 0.f, s1 = 0.f, ss = 0.f;
    for (int ti = 0; ti < NT_; ++ti) {
        const float v0 = T0[ti * 256 + tid], v1 = T1[ti * 256 + tid];
        s0 += v0; s1 += v1; ss += v0 * v0 + v1 * v1;
    }
    colred[tid] = (s0 * s0 + s1 * s1) - ss;  // = 2*sum_{ti<tj} T.T per col
    __syncthreads();
    if (tid == 0) {
        double g2 = 0.0;
        for (int i = 0; i < 256; ++i) g2 += (double)colred[i];
        double cross = -g2;  // -2 * sum_{ti<tj} (T0.T0 + T1.T1)
        double sufC0 = 0, sufC1 = 0, sufQ0 = 0, sufQ1 = 0;
        for (int ti = NT_ - 1; ti >= 0; --ti) {
            const double P0 = Pp[ti * 2], P1 = Pp[ti * 2 + 1];
            const double Q0 = Qq[ti * 2], Q1 = Qq[ti * 2 + 1];
            const double C0 = cntf[ti * 2], C1 = cntf[ti * 2 + 1];
            cross += P0 * sufC0 + P1 * sufC1 + sufQ0 * C0 + sufQ1 * C1
                   + (double)CEPS_ * (C0 * sufC0 + C1 * sufC1);
            sufC0 += C0; sufC1 += C1; sufQ0 += Q0; sufQ1 += Q1;
        }
        const double total = cross + (double)acc[0];
        const double cnt = (double)B_ * (double)(B_ - 1) / 2.0 + 1e-6;
        out[0] = (float)(total / cnt);
    }
}

extern "C" void kernel_launch(void* const* d_in, const int* in_sizes, int n_in,
                              void* d_out, int out_size, void* d_ws, size_t ws_size,
                              hipStream_t stream) {
    const float* x = (const float*)d_in[0];
    const int* label = (const int*)d_in[1];
    float* out = (float*)d_out;

    char* ws = (char*)d_ws;
    __bf16* xbf = (__bf16*)ws;
    float* fws = (float*)(ws + XBF_BYTES);
    float* acc = fws + OFF_ACC;

    prep_kernel<<<NT_, 256, 0, stream>>>(x, label, xbf, fws);
    tile_kernel<<<NBLK_, 256, 0, stream>>>((const unsigned short*)xbf, label, fws, acc);
    finalize_kernel<<<1, 256, 0, stream>>>(fws, out);
}

// Round 3
// 110.639 us; speedup vs baseline: 1.1144x; 1.1144x over previous
//
#include <hip/hip_runtime.h>
#include <hip/hip_bf16.h>

#define B_ 8192
#define D_ 256
#define EPS_ 1e-6f
#define MARGIN_ 1.0f
#define NT_ 64                               // 128-row tiles
#define NBLK_ (NT_ * (NT_ + 1) / 2)          // 2080
#define CEPS_ ((float)D_ * EPS_ * EPS_)

typedef float floatx4 __attribute__((ext_vector_type(4)));
typedef __bf16 bf16x4 __attribute__((ext_vector_type(4)));
typedef __bf16 bf16x8 __attribute__((ext_vector_type(8)));

typedef __attribute__((address_space(3))) unsigned int lds_uint_t;
typedef __attribute__((address_space(1))) const unsigned int g_uint_t;

__device__ __forceinline__ void g2l16(const unsigned short* g, unsigned short* l) {
    __builtin_amdgcn_global_load_lds((g_uint_t*)g, (lds_uint_t*)l, 16, 0, 0);
}

// ws float-region layout (after 4 MB bf16 matrix); all offsets in floats
#define XBF_BYTES (B_ * D_ * 2)
#define OFF_P      0        // p[i] = ||x||^2 + 2 eps sum      (8192)
#define OFF_Q      8192     // q[j] = ||x||^2 - 2 eps sum      (8192)
#define OFF_TP0    16384    // per-32-row-block col sums, label 0 (256*256)
#define OFF_TP1    81920    // label 1                           (256*256)
#define OFF_PPP    147456   // per-block [p-sum lab0, p-sum lab1] (512)
#define OFF_QQP    147968   // per-block [q-sum lab0, q-sum lab1] (512)
#define OFF_CP     148480   // per-block count of label 0         (256)
#define OFF_PMINP  148736   // per-block min p                    (256)
#define OFF_QMINP  148992   // per-block min q                    (256)
#define OFF_ACC    149248   // scalar accumulator

__device__ __forceinline__ int trif(int t) { return (t * (129 - t)) / 2; }

// ---------------- prep: 256 blocks x 32 rows; everything in one pass ----------------
__global__ __launch_bounds__(256) void prep_kernel(
    const float* __restrict__ x, const int* __restrict__ label,
    __bf16* __restrict__ xbf, float* __restrict__ fws) {
    float* p = fws + OFF_P;   float* q = fws + OFF_Q;
    float* Tp0 = fws + OFF_TP0; float* Tp1 = fws + OFF_TP1;
    float* PpP = fws + OFF_PPP; float* QqP = fws + OFF_QQP;
    float* CpP = fws + OFF_CP;
    float* pminP = fws + OFF_PMINP; float* qminP = fws + OFF_QMINP;
    float* acc = fws + OFF_ACC;

    __shared__ int lab_s[32];
    __shared__ float spl[32], sql[32];
    __shared__ float colbuf0[4][256], colbuf1[4][256];

    const int blk = blockIdx.x;
    const int r0 = blk * 32;
    const int tid = threadIdx.x, w = tid >> 6, lane = tid & 63;

    if (tid < 32) lab_s[tid] = label[r0 + tid];
    __syncthreads();

    floatx4 t0 = (floatx4)0.0f, t1 = (floatx4)0.0f;
    #pragma unroll
    for (int i = 0; i < 8; ++i) {
        const int rloc = w * 8 + i;
        const int row = r0 + rloc;
        const floatx4 v = *(const floatx4*)(x + (size_t)row * D_ + lane * 4);
        float sq = v[0]*v[0] + v[1]*v[1] + v[2]*v[2] + v[3]*v[3];
        float rs = v[0] + v[1] + v[2] + v[3];
        #pragma unroll
        for (int off = 32; off; off >>= 1) {
            sq += __shfl_down(sq, off);
            rs += __shfl_down(rs, off);
        }
        if (lane == 0) {
            const float pv = sq + 2.0f * EPS_ * rs;
            const float qv = sq - 2.0f * EPS_ * rs;
            p[row] = pv; q[row] = qv; spl[rloc] = pv; sql[rloc] = qv;
        }
        if (lab_s[rloc]) t1 += v; else t0 += v;   // wave-uniform branch
        bf16x4 h = { (__bf16)v[0], (__bf16)v[1], (__bf16)v[2], (__bf16)v[3] };
        *(bf16x4*)(xbf + (size_t)row * D_ + lane * 4) = h;
    }
    *(floatx4*)&colbuf0[w][lane * 4] = t0;
    *(floatx4*)&colbuf1[w][lane * 4] = t1;
    __syncthreads();

    // combine column partials across the 4 waves
    {
        const int c = tid;
        Tp0[blk * 256 + c] = colbuf0[0][c] + colbuf0[1][c] + colbuf0[2][c] + colbuf0[3][c];
        Tp1[blk * 256 + c] = colbuf1[0][c] + colbuf1[1][c] + colbuf1[2][c] + colbuf1[3][c];
    }
    // per-block scalar partials (first wave)
    if (tid < 64) {
        const bool va = tid < 32;
        const float pv = va ? spl[tid & 31] : 0.0f;
        const float qv = va ? sql[tid & 31] : 0.0f;
        const int lb = va ? lab_s[tid & 31] : 0;
        float p0 = (va && !lb) ? pv : 0.0f, p1 = (va && lb) ? pv : 0.0f;
        float q0 = (va && !lb) ? qv : 0.0f, q1 = (va && lb) ? qv : 0.0f;
        float c0 = (va && !lb) ? 1.0f : 0.0f;
        float pm = va ? pv : 1e30f, qm = va ? qv : 1e30f;
        #pragma unroll
        for (int off = 32; off; off >>= 1) {
            p0 += __shfl_down(p0, off); p1 += __shfl_down(p1, off);
            q0 += __shfl_down(q0, off); q1 += __shfl_down(q1, off);
            c0 += __shfl_down(c0, off);
            pm = fminf(pm, __shfl_down(pm, off));
            qm = fminf(qm, __shfl_down(qm, off));
        }
        if (tid == 0) {
            PpP[blk * 2 + 0] = p0; PpP[blk * 2 + 1] = p1;
            QqP[blk * 2 + 0] = q0; QqP[blk * 2 + 1] = q1;
            CpP[blk] = c0; pminP[blk] = pm; qminP[blk] = qm;
            if (blk == 0) acc[0] = 0.0f;
        }
    }
}

// ---------------- tile: dbuf single-barrier K-loop, detection epilogue ----------------
__global__ __launch_bounds__(256, 2) void tile_kernel(
    const unsigned short* __restrict__ xbf, const int* __restrict__ label,
    const float* __restrict__ fws, float* __restrict__ acc) {
    const float* p = fws + OFF_P;  const float* q = fws + OFF_Q;
    const float* pminP = fws + OFF_PMINP; const float* qminP = fws + OFF_QMINP;

    // closed-form triangular decode + fixup
    const int b = blockIdx.x;
    int ti = (int)((129.0f - sqrtf(fmaxf(16641.0f - 8.0f * (float)b, 0.0f))) * 0.5f);
    ti = max(0, min(63, ti));
    while (trif(ti + 1) <= b) ++ti;
    while (trif(ti) > b) --ti;
    const int tj = ti + (b - trif(ti));
    const int i0 = ti * 128, j0 = tj * 128;

    __shared__ __align__(16) unsigned short As[2][128 * 64];  // 2 x 16 KB
    __shared__ __align__(16) unsigned short Bs[2][128 * 64];  // 2 x 16 KB

    const int tid = threadIdx.x, wave = tid >> 6, lane = tid & 63;
    const int quad = lane >> 4, r = lane & 15;
    const int wm = wave >> 1, wn = wave & 1;

    // staging source (XOR-chunk swizzle, g2l dest = wave-uniform base + lane*16)
    const int r8 = lane >> 3, cch = lane & 7;
    const int sw = (cch ^ r8) * 8;
    const unsigned short* ga = xbf + (size_t)(i0 + wave * 32 + r8) * D_ + sw;
    const unsigned short* gb = xbf + (size_t)(j0 + wave * 32 + r8) * D_ + sw;

#define STAGE(k0, buf) do {                                                   \
        _Pragma("unroll")                                                     \
        for (int ps = 0; ps < 4; ++ps) {                                      \
            g2l16(ga + (k0) + ps * 8 * D_, &As[buf][(wave * 32 + ps * 8) * 64]); \
            g2l16(gb + (k0) + ps * 8 * D_, &Bs[buf][(wave * 32 + ps * 8) * 64]); \
        }                                                                     \
    } while (0)

    // fragment LDS offsets (shorts) within a buffer; k2 toggles via ^32
    int a_off[4], b_off[4];
    const int swr = (quad ^ (r & 7)) * 8;
    #pragma unroll
    for (int mt = 0; mt < 4; ++mt) a_off[mt] = (wm * 64 + mt * 16 + r) * 64 + swr;
    #pragma unroll
    for (int nt = 0; nt < 4; ++nt) b_off[nt] = (wn * 64 + nt * 16 + r) * 64 + swr;

    floatx4 accv[16];
    #pragma unroll
    for (int t = 0; t < 16; ++t) accv[t] = (floatx4)0.0f;

    STAGE(0, 0);
    #pragma unroll
    for (int k = 0; k < 4; ++k) {
        __syncthreads();                       // drains stage(k); protects buf (k+1)&1
        if (k < 3) STAGE((k + 1) * 64, (k + 1) & 1);
        const unsigned short* Ab = As[k & 1];
        const unsigned short* Bb = Bs[k & 1];
        #pragma unroll
        for (int k2 = 0; k2 < 2; ++k2) {
            const int kx = k2 * 32;
            bf16x8 af[4], bfr[4];
            #pragma unroll
            for (int mt = 0; mt < 4; ++mt) af[mt] = *(const bf16x8*)&Ab[a_off[mt] ^ kx];
            #pragma unroll
            for (int nt = 0; nt < 4; ++nt) bfr[nt] = *(const bf16x8*)&Bb[b_off[nt] ^ kx];
            #pragma unroll
            for (int mt = 0; mt < 4; ++mt)
                #pragma unroll
                for (int nt = 0; nt < 4; ++nt)
                    accv[mt * 4 + nt] = __builtin_amdgcn_mfma_f32_16x16x32_bf16(
                        af[mt], bfr[nt], accv[mt * 4 + nt], 0, 0, 0);
        }
    }
#undef STAGE

    if (ti != tj) {
        // detection only: any pair with sq_eps < 1 (i.e. gram > thr)?
        float m = -1e30f;
        #pragma unroll
        for (int t = 0; t < 16; ++t)
            m = fmaxf(m, fmaxf(fmaxf(accv[t][0], accv[t][1]), fmaxf(accv[t][2], accv[t][3])));
        const float pmn = fminf(fminf(pminP[4 * ti], pminP[4 * ti + 1]),
                                fminf(pminP[4 * ti + 2], pminP[4 * ti + 3]));
        const float qmn = fminf(fminf(qminP[4 * tj], qminP[4 * tj + 1]),
                                fminf(qminP[4 * tj + 2], qminP[4 * tj + 3]));
        const float thr = (pmn + qmn + CEPS_ - 1.0f) * 0.5f;
        if (__any(m > thr)) {
            // exact hinge slow path (expected never taken)
            float s = 0.0f;
            #pragma unroll
            for (int mt = 0; mt < 4; ++mt)
                #pragma unroll
                for (int nt = 0; nt < 4; ++nt)
                    #pragma unroll
                    for (int reg = 0; reg < 4; ++reg) {
                        const int gi = i0 + wm * 64 + mt * 16 + quad * 4 + reg;
                        const int gj = j0 + wn * 64 + nt * 16 + r;
                        const float sq = p[gi] + q[gj] + CEPS_ - 2.0f * accv[mt * 4 + nt][reg];
                        if (sq < 1.0f && label[gi] != label[gj]) {
                            const float d = sqrtf(fmaxf(sq, 1e-12f));
                            const float h = fmaxf(MARGIN_ - d, 0.0f);
                            s += h * h;
                        }
                    }
            #pragma unroll
            for (int off = 32; off; off >>= 1) s += __shfl_down(s, off);
            if (lane == 0) atomicAdd(acc, s);
        }
    } else {
        // diagonal: exact per-pair, strict upper triangle
        float s = 0.0f;
        #pragma unroll
        for (int mt = 0; mt < 4; ++mt)
            #pragma unroll
            for (int nt = 0; nt < 4; ++nt)
                #pragma unroll
                for (int reg = 0; reg < 4; ++reg) {
                    const int il = wm * 64 + mt * 16 + quad * 4 + reg;
                    const int jl = wn * 64 + nt * 16 + r;
                    if (il < jl) {
                        const int gi = i0 + il, gj = j0 + jl;
                        const float sq = p[gi] + q[gj] + CEPS_ - 2.0f * accv[mt * 4 + nt][reg];
                        const float d = sqrtf(fmaxf(sq, 1e-12f));
                        float v;
                        if (label[gi] == label[gj]) v = d * d;
                        else { const float h = fmaxf(MARGIN_ - d, 0.0f); v = h * h; }
                        s += v;
                    }
                }
        #pragma unroll
        for (int off = 32; off; off >>= 1) s += __shfl_down(s, off);
        if (lane == 0) atomicAdd(acc, s);
    }
}

// ---------------- finalize: parallel analytic cross-tile same-label sum ----------------
__global__ __launch_bounds__(256) void finalize_kernel(
    const float* __restrict__ fws, float* __restrict__ out) {
    const float* Tp0 = fws + OFF_TP0; const float* Tp1 = fws + OFF_TP1;
    const float* PpP = fws + OFF_PPP; const float* QqP = fws + OFF_QQP;
    const float* CpP = fws + OFF_CP;
    const float* acc = fws + OFF_ACC;

    __shared__ floatx4 s0q[4][64], s1q[4][64], ssq[4][64];
    __shared__ float g2s;
    __shared__ double tP0[64], tP1[64], tQ0[64], tQ1[64], tC0[64];

    const int tid = threadIdx.x;
    const int quad = tid & 63, tq = tid >> 6;

    // column reduction: thread handles col-quad `quad`, tiles ti ≡ tq (mod 4)
    floatx4 a0 = (floatx4)0.0f, a1 = (floatx4)0.0f, as = (floatx4)0.0f;
    for (int t = tq; t < 64; t += 4) {
        floatx4 T0 = (floatx4)0.0f, T1 = (floatx4)0.0f;
        #pragma unroll
        for (int b4 = 0; b4 < 4; ++b4) {
            const int blk = 4 * t + b4;
            T0 += *(const floatx4*)&Tp0[blk * 256 + quad * 4];
            T1 += *(const floatx4*)&Tp1[blk * 256 + quad * 4];
        }
        a0 += T0; as += T0 * T0;
        a1 += T1; as += T1 * T1;
    }
    s0q[tq][quad] = a0; s1q[tq][quad] = a1; ssq[tq][quad] = as;

    // per-tile scalars (second wave, parallel with wave-0 reduce below)
    if (tid >= 64 && tid < 128) {
        const int t = tid - 64;
        double P0 = 0, P1 = 0, Q0 = 0, Q1 = 0, C0 = 0;
        #pragma unroll
        for (int b4 = 0; b4 < 4; ++b4) {
            const int blk = 4 * t + b4;
            P0 += PpP[blk * 2]; P1 += PpP[blk * 2 + 1];
            Q0 += QqP[blk * 2]; Q1 += QqP[blk * 2 + 1];
            C0 += CpP[blk];
        }
        tP0[t] = P0; tP1[t] = P1; tQ0[t] = Q0; tQ1[t] = Q1; tC0[t] = C0;
    }
    __syncthreads();

    if (tid < 64) {
        const floatx4 S0 = s0q[0][tid] + s0q[1][tid] + s0q[2][tid] + s0q[3][tid];
        const floatx4 S1 = s1q[0][tid] + s1q[1][tid] + s1q[2][tid] + s1q[3][tid];
        const floatx4 SS = ssq[0][tid] + ssq[1][tid] + ssq[2][tid] + ssq[3][tid];
        float c = S0[0]*S0[0] + S0[1]*S0[1] + S0[2]*S0[2] + S0[3]*S0[3]
                + S1[0]*S1[0] + S1[1]*S1[1] + S1[2]*S1[2] + S1[3]*S1[3]
                - (SS[0] + SS[1] + SS[2] + SS[3]);
        #pragma unroll
        for (int off = 32; off; off >>= 1) c += __shfl_down(c, off);
        if (tid == 0) g2s = c;   // = 2*sum_{ti<tj} (T0ti·T0tj + T1ti·T1tj)
    }
    __syncthreads();

    if (tid == 0) {
        double cross = -(double)g2s;
        double sufC0 = 0, sufC1 = 0, sufQ0 = 0, sufQ1 = 0;
        for (int t = 63; t >= 0; --t) {
            const double C0 = tC0[t], C1 = 32.0 * 4.0 - C0;  // 128 rows/tile
            cross += tP0[t] * sufC0 + tP1[t] * sufC1 + sufQ0 * C0 + sufQ1 * C1
                   + (double)CEPS_ * (C0 * sufC0 + C1 * sufC1);
            sufC0 += C0; sufC1 += C1; sufQ0 += tQ0[t]; sufQ1 += tQ1[t];
        }
        const double total = cross + (double)acc[0];
        const double cnt = (double)B_ * (double)(B_ - 1) / 2.0 + 1e-6;
        out[0] = (float)(total / cnt);
    }
}

extern "C" void kernel_launch(void* const* d_in, const int* in_sizes, int n_in,
                              void* d_out, int out_size, void* d_ws, size_t ws_size,
                              hipStream_t stream) {
    const float* x = (const float*)d_in[0];
    const int* label = (const int*)d_in[1];
    float* out = (float*)d_out;

    char* ws = (char*)d_ws;
    __bf16* xbf = (__bf16*)ws;
    float* fws = (float*)(ws + XBF_BYTES);
    float* acc = fws + OFF_ACC;

    prep_kernel<<<B_ / 32, 256, 0, stream>>>(x, label, xbf, fws);
    tile_kernel<<<NBLK_, 256, 0, stream>>>((const unsigned short*)xbf, label, fws, acc);
    finalize_kernel<<<1, 256, 0, stream>>>(fws, out);
}